// Round 9
// baseline (59.882 us; speedup 1.0000x reference)
//
#include <hip/hip_runtime.h>
#include <hip/hip_bf16.h>

#define NB 4
#define NN 512
#define ND 128
#define NH 4
#define NK 32

constexpr float EPSV = 1e-6f;
constexpr float CF   = 2.8853900817779268f;   // 2/ln2
constexpr float L2E  = 1.4426950408889634f;   // log2(e)
constexpr float LN2V = 0.6931471805599453f;   // ln(2)
constexpr float EXPCUT = 25.0f;               // skip terms < e^-25 (rigorous bound)

__device__ __forceinline__ float4 ld4(const float* __restrict__ p) {
  return *reinterpret_cast<const float4*>(p);
}

// Kernel 1: x2 + projections ai' = (x@W1a + b1)*CF, aj' = (x@W1b)*CF.
// Block 0 thread 0 additionally computes the rigorous skip threshold dnth.
__global__ __launch_bounds__(256) void dgf_proj(
    const float* __restrict__ x, const float* __restrict__ W1,
    const float* __restrict__ b1, const float* __restrict__ W2,
    const float* __restrict__ b2, float* __restrict__ ai2,
    float* __restrict__ aj2, float* __restrict__ x2n,
    float* __restrict__ dnthp) {
  __shared__ float xr[8][ND];
  const int t = threadIdx.x;
  const int blk = blockIdx.x;
  const int b = blk >> 6;
  const int n0 = (blk & 63) << 3;
  const float* xb = x + (size_t)(b * NN + n0) * ND;
  {
    const int row = t >> 5, c = t & 31;
    *reinterpret_cast<float4*>(&xr[row][c * 4]) = ld4(xb + row * ND + c * 4);
  }
  if (blk == 0 && t == 0) {
    // sigma <= softplus(max_h(b2 + sum_k |W2|)); terms with
    // dist > EXPCUT*(2*sigmax^2+eps) are <= e^-EXPCUT -> skippable.
    float m = -1e30f;
    for (int h = 0; h < NH; ++h) {
      float sa = b2[h];
      for (int k = 0; k < NK; ++k) sa += fabsf(W2[h * NK + k]);
      m = fmaxf(m, sa);
    }
    const float e2 = __builtin_amdgcn_exp2f(m * L2E);
    const float lp = __builtin_amdgcn_logf(e2 + 1.f) * LN2V;
    const float sm = (m > 15.f) ? m : lp;          // softplus(m)
    dnthp[0] = -L2E * EXPCUT * fmaf(2.f * sm, sm, EPSV);
  }
  __syncthreads();
  if (t < 8) {
    float s = 0.f;
    for (int d = 0; d < ND; ++d) s = fmaf(xr[t][d], xr[t][d], s);
    x2n[b * NN + n0 + t] = s;
  }
  const int h = t >> 6, part = (t >> 5) & 1, k = t & 31;
  const float* w1p = W1 + (size_t)(h * 256 + part * 128) * NK + k;
  float acc[8] = {0.f, 0.f, 0.f, 0.f, 0.f, 0.f, 0.f, 0.f};
  for (int d = 0; d < ND; d += 4) {
    const float w0 = w1p[(d + 0) * NK];
    const float w1v = w1p[(d + 1) * NK];
    const float w2v = w1p[(d + 2) * NK];
    const float w3v = w1p[(d + 3) * NK];
#pragma unroll
    for (int row = 0; row < 8; ++row) {
      const float4 xv = *reinterpret_cast<const float4*>(&xr[row][d]);
      float a = acc[row];
      a = fmaf(xv.x, w0, a);
      a = fmaf(xv.y, w1v, a);
      a = fmaf(xv.z, w2v, a);
      a = fmaf(xv.w, w3v, a);
      acc[row] = a;
    }
  }
  const float bb = (part == 0) ? b1[h * NK + k] : 0.f;
  float* outp = (part == 0) ? ai2 : aj2;
#pragma unroll
  for (int row = 0; row < 8; ++row) {
    outp[((size_t)(b * NN + n0 + row) * NH + h) * NK + k] = (acc[row] + bb) * CF;
  }
}

// Kernel 2: adj tile (4 i-rows x 128 j) = inline dist + heads with
// BARRIER-FREE per-wave far-pair skip. grid = B*(N/4)*(N/128) = 2048 blocks,
// 128 threads; thread t -> j = jq*128+t, all 4 i-rows (r=4 ILP).
__global__ __launch_bounds__(128, 4) void dgf_adjmat(
    const float* __restrict__ x, const float* __restrict__ W2,
    const float* __restrict__ b2, const float* __restrict__ ai2,
    const float* __restrict__ aj2, const float* __restrict__ x2n,
    const float* __restrict__ dnthp, float* __restrict__ adjm) {
  __shared__ float4 xi4[4 * 32];     // 4 i-rows of x    2KB
  __shared__ float4 ai2s4[4 * 32];   // 4 i-rows of ai'  2KB
  __shared__ float4 w2s4[32];        // -2*W2 [h][k]
  __shared__ float x2is[4];
  __shared__ float b2s[4];           // b2[h] + sum_k W2[h][k]
  const int t = threadIdx.x;
  const int blk = blockIdx.x;
  const int jq = blk & 3;
  const int iq = (blk >> 2) & 127;
  const int b  = blk >> 9;
  const int i0 = iq << 2;
  const int j  = (jq << 7) + t;

  {
    const int r = t >> 5, c = t & 31;
    xi4[t]   = ld4(x   + (size_t)(b * NN + i0 + r) * ND + c * 4);
    ai2s4[t] = ld4(ai2 + (size_t)(b * NN + i0 + r) * (NH * NK) + c * 4);
  }
  if (t < 32) {
    const float4 w = ld4(W2 + t * 4);
    float4 wn;
    wn.x = -2.f * w.x; wn.y = -2.f * w.y; wn.z = -2.f * w.z; wn.w = -2.f * w.w;
    w2s4[t] = wn;
  }
  if (t < 4) {
    x2is[t] = x2n[b * NN + i0 + t];
    float sw = 0.f;
    for (int k = 0; k < NK; ++k) sw += W2[t * NK + k];
    b2s[t] = b2[t] + sw;
  }
  __syncthreads();

  // ---- inline dist for this tile: dn[r] = -L2E * dist(i0+r, j) ----
  float dn[4];
  {
    float g[4] = {0.f, 0.f, 0.f, 0.f};
    const float* xj = x + (size_t)(b * NN + j) * ND;
    for (int c = 0; c < 32; ++c) {
      const float4 a = ld4(xj + c * 4);
#pragma unroll
      for (int r = 0; r < 4; ++r) {
        const float4 xv = xi4[r * 32 + c];
        float u = g[r];
        u = fmaf(xv.x, a.x, u); u = fmaf(xv.y, a.y, u);
        u = fmaf(xv.z, a.z, u); u = fmaf(xv.w, a.w, u);
        g[r] = u;
      }
    }
    const float x2j = x2n[b * NN + j];
#pragma unroll
    for (int r = 0; r < 4; ++r)
      dn[r] = -L2E * fmaxf(x2is[r] + x2j - 2.f * g[r], 0.f);
  }

  // ---- heads, wave-skippable (no barrier after this point) ----
  float adjv[4] = {0.f, 0.f, 0.f, 0.f};
  {
    const float dnth = dnthp[0];
    const bool need = (dn[0] > dnth) || (dn[1] > dnth) ||
                      (dn[2] > dnth) || (dn[3] > dnth);
    if (__any(need)) {
      const float* ajp = aj2 + (size_t)(b * NN + j) * (NH * NK);
      for (int h = 0; h < NH; ++h) {
        float4 aj[8];
#pragma unroll
        for (int c = 0; c < 8; ++c) aj[c] = ld4(ajp + h * NK + c * 4);
        float s[4] = {0.f, 0.f, 0.f, 0.f};
#pragma unroll
        for (int kc = 0; kc < 8; ++kc) {
          const float4 w2c = w2s4[h * 8 + kc];   // already -2*W2
          const float4 ajc = aj[kc];
#pragma unroll
          for (int r = 0; r < 4; ++r) {
            const float4 ac = ai2s4[r * 32 + h * 8 + kc];
            float z, rc, sr = s[r];
            z = ac.x + ajc.x;
            rc = __builtin_amdgcn_rcpf(__builtin_amdgcn_exp2f(z) + 1.f);
            sr = fmaf(w2c.x, rc, sr);
            z = ac.y + ajc.y;
            rc = __builtin_amdgcn_rcpf(__builtin_amdgcn_exp2f(z) + 1.f);
            sr = fmaf(w2c.y, rc, sr);
            z = ac.z + ajc.z;
            rc = __builtin_amdgcn_rcpf(__builtin_amdgcn_exp2f(z) + 1.f);
            sr = fmaf(w2c.z, rc, sr);
            z = ac.w + ajc.w;
            rc = __builtin_amdgcn_rcpf(__builtin_amdgcn_exp2f(z) + 1.f);
            sr = fmaf(w2c.w, rc, sr);
            s[r] = sr;
          }
        }
#pragma unroll
        for (int r = 0; r < 4; ++r) {
          const float si = s[r] + b2s[h];       // + (b2 + sum_k W2)
          const float e2 = __builtin_amdgcn_exp2f(si * L2E);
          const float lp = __builtin_amdgcn_logf(e2 + 1.f) * LN2V;
          const float sp = (si > 15.f) ? si : lp;   // softplus
          const float den = fmaf(2.f * sp, sp, EPSV);
          const float rr = __builtin_amdgcn_rcpf(den);
          adjv[r] += __builtin_amdgcn_exp2f(dn[r] * rr);
        }
      }
    }
  }
  {
    float* ap = adjm + ((size_t)(b * NN + i0)) * NN + j;
#pragma unroll
    for (int r = 0; r < 4; ++r) ap[(size_t)r * NN] = adjv[r] * 0.25f;
  }
}

// Kernel 3: h_out = adj @ x ; out = h_out @ Wp + bp.
// grid = B*(N/4) = 512 blocks, 512 threads; block (b, i0..i0+3).
__global__ __launch_bounds__(512, 4) void dgf_hout(
    const float* __restrict__ x, const float* __restrict__ Wp,
    const float* __restrict__ bp, const float* __restrict__ adjm,
    float* __restrict__ out) {
  __shared__ float4 adjs4[512];      // [j] -> (r0..r3)  8KB
  __shared__ float pcbuf[16 * 512];  // 32KB: C partials; reused as pd in D
  __shared__ float hsT[4 * 128];     // [r][e]  2KB
  const int t = threadIdx.x;
  const int blk = blockIdx.x;
  const int b = blk >> 7;
  const int i0 = (blk & 127) << 2;

  // stage adj rows with transpose into [j][r]
  {
    const int r = t >> 7, j0 = (t & 127) << 2;
    const float4 a = ld4(adjm + ((size_t)(b * NN + i0 + r)) * NN + j0);
    float* as = reinterpret_cast<float*>(adjs4);
    as[(j0 + 0) * 4 + r] = a.x;
    as[(j0 + 1) * 4 + r] = a.y;
    as[(j0 + 2) * 4 + r] = a.z;
    as[(j0 + 3) * 4 + r] = a.w;
  }
  __syncthreads();

  // Phase C: h_out = adj @ x
  {
    const int dg = t & 31, jp = t >> 5;   // 16 j-groups of 32 j's
    float4 f0 = {0,0,0,0}, f1 = {0,0,0,0}, f2 = {0,0,0,0}, f3 = {0,0,0,0};
    const float* xb = x + (size_t)(b * NN) * ND;
    for (int u = 0; u < 32; ++u) {
      const int j = jp * 32 + u;
      const float4 a = adjs4[j];
      const float4 xv = ld4(xb + (size_t)j * ND + dg * 4);
      f0.x = fmaf(a.x, xv.x, f0.x); f0.y = fmaf(a.x, xv.y, f0.y);
      f0.z = fmaf(a.x, xv.z, f0.z); f0.w = fmaf(a.x, xv.w, f0.w);
      f1.x = fmaf(a.y, xv.x, f1.x); f1.y = fmaf(a.y, xv.y, f1.y);
      f1.z = fmaf(a.y, xv.z, f1.z); f1.w = fmaf(a.y, xv.w, f1.w);
      f2.x = fmaf(a.z, xv.x, f2.x); f2.y = fmaf(a.z, xv.y, f2.y);
      f2.z = fmaf(a.z, xv.z, f2.z); f2.w = fmaf(a.z, xv.w, f2.w);
      f3.x = fmaf(a.w, xv.x, f3.x); f3.y = fmaf(a.w, xv.y, f3.y);
      f3.z = fmaf(a.w, xv.z, f3.z); f3.w = fmaf(a.w, xv.w, f3.w);
    }
    float4* pc4 = reinterpret_cast<float4*>(pcbuf);
    pc4[jp * 128 + 0 * 32 + dg] = f0;
    pc4[jp * 128 + 1 * 32 + dg] = f1;
    pc4[jp * 128 + 2 * 32 + dg] = f2;
    pc4[jp * 128 + 3 * 32 + dg] = f3;
  }
  __syncthreads();
  {
    float v = 0.f;
#pragma unroll
    for (int jp = 0; jp < 16; ++jp) v += pcbuf[jp * 512 + t];
    hsT[t] = v;   // t = r*128 + e
  }
  __syncthreads();

  // Phase D: out = h_out @ Wp + bp
  {
    const int d = t & 127, eh = t >> 7;
    float a0 = 0.f, a1 = 0.f, a2 = 0.f, a3 = 0.f;
    for (int ee = 0; ee < 32; ++ee) {
      const int e = eh * 32 + ee;
      const float w = Wp[(size_t)e * ND + d];
      a0 = fmaf(hsT[0 * 128 + e], w, a0);
      a1 = fmaf(hsT[1 * 128 + e], w, a1);
      a2 = fmaf(hsT[2 * 128 + e], w, a2);
      a3 = fmaf(hsT[3 * 128 + e], w, a3);
    }
    float* pd = pcbuf;
    pd[eh * 512 + 0 * 128 + d] = a0;
    pd[eh * 512 + 1 * 128 + d] = a1;
    pd[eh * 512 + 2 * 128 + d] = a2;
    pd[eh * 512 + 3 * 128 + d] = a3;
  }
  __syncthreads();
  {
    const int r = t >> 7, d = t & 127;
    const float v = pcbuf[0 * 512 + t] + pcbuf[1 * 512 + t] +
                    pcbuf[2 * 512 + t] + pcbuf[3 * 512 + t] + bp[d];
    out[(size_t)(b * NN + i0 + r) * ND + d] = v;
  }
}

// Fallback: fused kernel (R3-verified), used if ws is too small.
__global__ __launch_bounds__(512, 4) void dgf_fused(
    const float* __restrict__ x, const float* __restrict__ W2,
    const float* __restrict__ b2, const float* __restrict__ Wp,
    const float* __restrict__ bp, const float* __restrict__ ai2,
    const float* __restrict__ aj2, const float* __restrict__ x2n,
    float* __restrict__ out) {
  __shared__ float4 xi4[4 * 32];
  __shared__ float4 ai2s4[4 * 32];
  __shared__ float4 w2s4[32];
  __shared__ float x2is[4];
  __shared__ float b2s[4];
  __shared__ float4 adjs4[512];
  __shared__ float pcbuf[16 * 512];
  __shared__ float hsT[4 * 128];
  const int t = threadIdx.x;
  const int blk = blockIdx.x;
  const int b = blk >> 7;
  const int i0 = (blk & 127) << 2;

  if (t < 128) {
    const int r = t >> 5;
    const int c = t & 31;
    xi4[t]   = ld4(x   + (size_t)(b * NN + i0 + r) * ND + c * 4);
    ai2s4[t] = ld4(ai2 + (size_t)(b * NN + i0 + r) * (NH * NK) + c * 4);
  } else if (t < 160) {
    const float4 w = ld4(W2 + (t - 128) * 4);
    float4 wn;
    wn.x = -2.f * w.x; wn.y = -2.f * w.y; wn.z = -2.f * w.z; wn.w = -2.f * w.w;
    w2s4[t - 128] = wn;
  } else if (t < 164) {
    x2is[t - 160] = x2n[b * NN + i0 + (t - 160)];
  } else if (t < 168) {
    const int h = t - 164;
    float sw = 0.f;
    for (int k = 0; k < NK; ++k) sw += W2[h * NK + k];
    b2s[h] = b2[h] + sw;
  }
  __syncthreads();

  float dn[4];
  {
    float g[4] = {0.f, 0.f, 0.f, 0.f};
    const float* xj = x + (size_t)(b * NN + t) * ND;
    for (int c = 0; c < 32; ++c) {
      const float4 a = ld4(xj + c * 4);
#pragma unroll
      for (int r = 0; r < 4; ++r) {
        const float4 xv = xi4[r * 32 + c];
        float u = g[r];
        u = fmaf(xv.x, a.x, u); u = fmaf(xv.y, a.y, u);
        u = fmaf(xv.z, a.z, u); u = fmaf(xv.w, a.w, u);
        g[r] = u;
      }
    }
    const float x2j = x2n[b * NN + t];
#pragma unroll
    for (int r = 0; r < 4; ++r)
      dn[r] = -L2E * fmaxf(x2is[r] + x2j - 2.f * g[r], 0.f);
  }

  float adjv[4] = {0.f, 0.f, 0.f, 0.f};
  {
    const float* ajp = aj2 + (size_t)(b * NN + t) * (NH * NK);
    for (int h = 0; h < NH; ++h) {
      float4 aj[8];
#pragma unroll
      for (int c = 0; c < 8; ++c) aj[c] = ld4(ajp + h * NK + c * 4);
      float s[4] = {0.f, 0.f, 0.f, 0.f};
#pragma unroll
      for (int kc = 0; kc < 8; ++kc) {
        const float4 w2c = w2s4[h * 8 + kc];
        const float4 ajc = aj[kc];
#pragma unroll
        for (int r = 0; r < 4; ++r) {
          const float4 ac = ai2s4[r * 32 + h * 8 + kc];
          float z, rc, sr = s[r];
          z = ac.x + ajc.x;
          rc = __builtin_amdgcn_rcpf(__builtin_amdgcn_exp2f(z) + 1.f);
          sr = fmaf(w2c.x, rc, sr);
          z = ac.y + ajc.y;
          rc = __builtin_amdgcn_rcpf(__builtin_amdgcn_exp2f(z) + 1.f);
          sr = fmaf(w2c.y, rc, sr);
          z = ac.z + ajc.z;
          rc = __builtin_amdgcn_rcpf(__builtin_amdgcn_exp2f(z) + 1.f);
          sr = fmaf(w2c.z, rc, sr);
          z = ac.w + ajc.w;
          rc = __builtin_amdgcn_rcpf(__builtin_amdgcn_exp2f(z) + 1.f);
          sr = fmaf(w2c.w, rc, sr);
          s[r] = sr;
        }
      }
#pragma unroll
      for (int r = 0; r < 4; ++r) {
        const float si = s[r] + b2s[h];
        const float e2 = __builtin_amdgcn_exp2f(si * L2E);
        const float lp = __builtin_amdgcn_logf(e2 + 1.f) * LN2V;
        const float sp = (si > 15.f) ? si : lp;
        const float den = fmaf(2.f * sp, sp, EPSV);
        const float rr = __builtin_amdgcn_rcpf(den);
        adjv[r] += __builtin_amdgcn_exp2f(dn[r] * rr);
      }
    }
  }
  {
    float4 v;
    v.x = adjv[0] * 0.25f; v.y = adjv[1] * 0.25f;
    v.z = adjv[2] * 0.25f; v.w = adjv[3] * 0.25f;
    adjs4[t] = v;
  }
  __syncthreads();

  {
    const int dg = t & 31, jp = t >> 5;
    float4 f0 = {0,0,0,0}, f1 = {0,0,0,0}, f2 = {0,0,0,0}, f3 = {0,0,0,0};
    const float* xb = x + (size_t)(b * NN) * ND;
    for (int u = 0; u < 32; ++u) {
      const int j = jp * 32 + u;
      const float4 a = adjs4[j];
      const float4 xv = ld4(xb + (size_t)j * ND + dg * 4);
      f0.x = fmaf(a.x, xv.x, f0.x); f0.y = fmaf(a.x, xv.y, f0.y);
      f0.z = fmaf(a.x, xv.z, f0.z); f0.w = fmaf(a.x, xv.w, f0.w);
      f1.x = fmaf(a.y, xv.x, f1.x); f1.y = fmaf(a.y, xv.y, f1.y);
      f1.z = fmaf(a.y, xv.z, f1.z); f1.w = fmaf(a.y, xv.w, f1.w);
      f2.x = fmaf(a.z, xv.x, f2.x); f2.y = fmaf(a.z, xv.y, f2.y);
      f2.z = fmaf(a.z, xv.z, f2.z); f2.w = fmaf(a.z, xv.w, f2.w);
      f3.x = fmaf(a.w, xv.x, f3.x); f3.y = fmaf(a.w, xv.y, f3.y);
      f3.z = fmaf(a.w, xv.z, f3.z); f3.w = fmaf(a.w, xv.w, f3.w);
    }
    float4* pc4 = reinterpret_cast<float4*>(pcbuf);
    pc4[jp * 128 + 0 * 32 + dg] = f0;
    pc4[jp * 128 + 1 * 32 + dg] = f1;
    pc4[jp * 128 + 2 * 32 + dg] = f2;
    pc4[jp * 128 + 3 * 32 + dg] = f3;
  }
  __syncthreads();
  {
    float v = 0.f;
#pragma unroll
    for (int jp = 0; jp < 16; ++jp) v += pcbuf[jp * 512 + t];
    hsT[t] = v;
  }
  __syncthreads();
  {
    const int d = t & 127, eh = t >> 7;
    float a0 = 0.f, a1 = 0.f, a2 = 0.f, a3 = 0.f;
    for (int ee = 0; ee < 32; ++ee) {
      const int e = eh * 32 + ee;
      const float w = Wp[(size_t)e * ND + d];
      a0 = fmaf(hsT[0 * 128 + e], w, a0);
      a1 = fmaf(hsT[1 * 128 + e], w, a1);
      a2 = fmaf(hsT[2 * 128 + e], w, a2);
      a3 = fmaf(hsT[3 * 128 + e], w, a3);
    }
    float* pd = pcbuf;
    pd[eh * 512 + 0 * 128 + d] = a0;
    pd[eh * 512 + 1 * 128 + d] = a1;
    pd[eh * 512 + 2 * 128 + d] = a2;
    pd[eh * 512 + 3 * 128 + d] = a3;
  }
  __syncthreads();
  {
    const int d = t & 127;
    const float v = pcbuf[0 * 512 + t] + pcbuf[1 * 512 + t] +
                    pcbuf[2 * 512 + t] + pcbuf[3 * 512 + t] + bp[d];
    const int r = t >> 7;
    out[(size_t)(b * NN + i0 + r) * ND + d] = v;
  }
}

extern "C" void kernel_launch(void* const* d_in, const int* in_sizes, int n_in,
                              void* d_out, int out_size, void* d_ws, size_t ws_size,
                              hipStream_t stream) {
  const float* x  = (const float*)d_in[0];
  const float* W1 = (const float*)d_in[1];
  const float* b1 = (const float*)d_in[2];
  const float* W2 = (const float*)d_in[3];
  const float* b2 = (const float*)d_in[4];
  const float* Wp = (const float*)d_in[5];
  const float* bp = (const float*)d_in[6];
  float* out = (float*)d_out;

  const size_t nProj = (size_t)NB * NN * NH * NK;   // 262144
  const size_t nX2   = (size_t)NB * NN;             // 2048
  const size_t nAdj  = (size_t)NB * NN * NN;        // 1048576

  float* aj2 = (float*)d_ws;
  float* ai2 = aj2 + nProj;
  float* x2n = ai2 + nProj;
  float* dnt = x2n + nX2;           // 4 floats (1 used)
  float* adj = dnt + 4;

  dgf_proj<<<NB * NN / 8, 256, 0, stream>>>(x, W1, b1, W2, b2, ai2, aj2, x2n,
                                            dnt);

  if (ws_size >= (2 * nProj + nX2 + 4 + nAdj) * sizeof(float)) {
    dgf_adjmat<<<NB * (NN / 4) * (NN / 128), 128, 0, stream>>>(
        x, W2, b2, ai2, aj2, x2n, dnt, adj);
    dgf_hout<<<NB * (NN / 4), 512, 0, stream>>>(x, Wp, bp, adj, out);
  } else {
    dgf_fused<<<NB * (NN / 4), 512, 0, stream>>>(x, W2, b2, Wp, bp, ai2, aj2,
                                                 x2n, out);
  }
}

// Round 10
// 57.944 us; speedup vs baseline: 1.0335x; 1.0335x over previous
//
#include <hip/hip_runtime.h>
#include <hip/hip_bf16.h>

#define NB 4
#define NN 512
#define ND 128
#define NH 4
#define NK 32

constexpr float EPSV = 1e-6f;
constexpr float CF   = 2.8853900817779268f;   // 2/ln2
constexpr float L2E  = 1.4426950408889634f;   // log2(e)
constexpr float LN2V = 0.6931471805599453f;   // ln(2)
constexpr float EXPCUT = 25.0f;               // skip terms < e^-25 (rigorous bound)

__device__ __forceinline__ float4 ld4(const float* __restrict__ p) {
  return *reinterpret_cast<const float4*>(p);
}

// Kernel 1: x2 + projections. Row layouts: ai2 (with bias, *CF), aj2 (*CF).
// Transposed layouts (j-contiguous): ajT[b][h*32+k][j], xT[b][d][j].
// Block 0 thread 0 computes the rigorous skip threshold dnth.
__global__ __launch_bounds__(256) void dgf_proj(
    const float* __restrict__ x, const float* __restrict__ W1,
    const float* __restrict__ b1, const float* __restrict__ W2,
    const float* __restrict__ b2, float* __restrict__ ai2,
    float* __restrict__ aj2, float* __restrict__ ajT,
    float* __restrict__ xT, float* __restrict__ x2n,
    float* __restrict__ dnthp) {
  __shared__ float xr[8][ND];
  const int t = threadIdx.x;
  const int blk = blockIdx.x;
  const int b = blk >> 6;
  const int n0 = (blk & 63) << 3;
  const float* xb = x + (size_t)(b * NN + n0) * ND;
  {
    const int row = t >> 5, c = t & 31;
    *reinterpret_cast<float4*>(&xr[row][c * 4]) = ld4(xb + row * ND + c * 4);
  }
  if (blk == 0 && t == 0) {
    // sigma <= softplus(max_h(b2 + sum_k |W2|)); terms with
    // dist > EXPCUT*(2*sigmax^2+eps) are <= e^-EXPCUT -> skippable.
    float m = -1e30f;
    for (int h = 0; h < NH; ++h) {
      float sa = b2[h];
      for (int k = 0; k < NK; ++k) sa += fabsf(W2[h * NK + k]);
      m = fmaxf(m, sa);
    }
    const float e2 = __builtin_amdgcn_exp2f(m * L2E);
    const float lp = __builtin_amdgcn_logf(e2 + 1.f) * LN2V;
    const float sm = (m > 15.f) ? m : lp;          // softplus(m)
    dnthp[0] = -L2E * EXPCUT * fmaf(2.f * sm, sm, EPSV);
  }
  __syncthreads();
  if (t < 8) {
    float s = 0.f;
    for (int d = 0; d < ND; ++d) s = fmaf(xr[t][d], xr[t][d], s);
    x2n[b * NN + n0 + t] = s;
  }
  // xT writes (transposed x): 1024 elems, 4 per thread
  if (xT) {
#pragma unroll
    for (int w = 0; w < 4; ++w) {
      const int idx = t + w * 256;
      const int d = idx >> 3, row = idx & 7;
      xT[((size_t)b * ND + d) * NN + n0 + row] = xr[row][d];
    }
  }
  const int h = t >> 6, part = (t >> 5) & 1, k = t & 31;
  const float* w1p = W1 + (size_t)(h * 256 + part * 128) * NK + k;
  float acc[8] = {0.f, 0.f, 0.f, 0.f, 0.f, 0.f, 0.f, 0.f};
  for (int d = 0; d < ND; d += 4) {
    const float w0 = w1p[(d + 0) * NK];
    const float w1v = w1p[(d + 1) * NK];
    const float w2v = w1p[(d + 2) * NK];
    const float w3v = w1p[(d + 3) * NK];
#pragma unroll
    for (int row = 0; row < 8; ++row) {
      const float4 xv = *reinterpret_cast<const float4*>(&xr[row][d]);
      float a = acc[row];
      a = fmaf(xv.x, w0, a);
      a = fmaf(xv.y, w1v, a);
      a = fmaf(xv.z, w2v, a);
      a = fmaf(xv.w, w3v, a);
      acc[row] = a;
    }
  }
  if (part == 0) {
    const float bb = b1[h * NK + k];
#pragma unroll
    for (int row = 0; row < 8; ++row) {
      ai2[((size_t)(b * NN + n0 + row) * NH + h) * NK + k] =
          (acc[row] + bb) * CF;
    }
  } else {
#pragma unroll
    for (int row = 0; row < 8; ++row) {
      const float v = acc[row] * CF;
      aj2[((size_t)(b * NN + n0 + row) * NH + h) * NK + k] = v;
      if (ajT)
        ajT[((size_t)(b * 128 + h * NK + k)) * NN + n0 + row] = v;
    }
  }
}

// Kernel 2: fused gram(via xT, coalesced) + heads(via ajT, coalesced,
// wave-skippable) + C (adj@x) + D (proj).
// grid = B*(N/4) = 512 blocks, 512 threads; block (b, i0..i0+3); thread = j.
__global__ __launch_bounds__(512, 4) void dgf_adj2(
    const float* __restrict__ x, const float* __restrict__ W2,
    const float* __restrict__ b2, const float* __restrict__ Wp,
    const float* __restrict__ bp, const float* __restrict__ ai2,
    const float* __restrict__ ajT, const float* __restrict__ xT,
    const float* __restrict__ x2n, const float* __restrict__ dnthp,
    float* __restrict__ out) {
  __shared__ float4 xis4[128];       // xi transposed: [d] -> (r0..r3)  2KB
  __shared__ float4 ai2s4[4 * 32];   // 4 i-rows of ai'  2KB
  __shared__ float4 w2s4[32];        // -2*W2 [h][k]
  __shared__ float x2is[4];
  __shared__ float b2s[4];           // b2[h] + sum_k W2[h][k]
  __shared__ float4 adjs4[512];      // [j] -> (r0..r3)  8KB
  __shared__ float pcbuf[16 * 512];  // 32KB: C partials; reused as pd in D
  __shared__ float hsT[4 * 128];     // [r][e]  2KB
  const int t = threadIdx.x;
  const int blk = blockIdx.x;
  const int b = blk >> 7;
  const int i0 = (blk & 127) << 2;

  // ---- Phase A: stage ----
  if (t < 128) {
    const int r = t >> 5, c = t & 31;
    const float4 v = ld4(x + (size_t)(b * NN + i0 + r) * ND + c * 4);
    float* xisf = reinterpret_cast<float*>(xis4);
    xisf[(4 * c + 0) * 4 + r] = v.x;
    xisf[(4 * c + 1) * 4 + r] = v.y;
    xisf[(4 * c + 2) * 4 + r] = v.z;
    xisf[(4 * c + 3) * 4 + r] = v.w;
    ai2s4[t] = ld4(ai2 + (size_t)(b * NN + i0 + r) * (NH * NK) + c * 4);
  } else if (t < 160) {
    const float4 w = ld4(W2 + (t - 128) * 4);
    float4 wn;
    wn.x = -2.f * w.x; wn.y = -2.f * w.y; wn.z = -2.f * w.z; wn.w = -2.f * w.w;
    w2s4[t - 128] = wn;
  } else if (t < 164) {
    const int h = t - 160;
    float sw = 0.f;
    for (int k = 0; k < NK; ++k) sw += W2[h * NK + k];
    b2s[h] = b2[h] + sw;
    x2is[h] = x2n[b * NN + i0 + h];
  }
  __syncthreads();

  // ---- B1: gram via transposed x (coalesced: lane = j) ----
  float dn[4];
  {
    float g[4] = {0.f, 0.f, 0.f, 0.f};
    const float* xTb = xT + (size_t)b * ND * NN + t;
#pragma unroll 8
    for (int d = 0; d < ND; ++d) {
      const float xv = xTb[(size_t)d * NN];
      const float4 xi = xis4[d];
      g[0] = fmaf(xi.x, xv, g[0]);
      g[1] = fmaf(xi.y, xv, g[1]);
      g[2] = fmaf(xi.z, xv, g[2]);
      g[3] = fmaf(xi.w, xv, g[3]);
    }
    const float x2j = x2n[b * NN + t];
#pragma unroll
    for (int r = 0; r < 4; ++r)
      dn[r] = -L2E * fmaxf(x2is[r] + x2j - 2.f * g[r], 0.f);
  }

  // ---- B2 (wave-skippable): sum_k w*tanh = sum_k w + sum_k (-2w)*sigmoid ----
  float adjv[4] = {0.f, 0.f, 0.f, 0.f};
  {
    const float dnth = dnthp[0];
    const bool need = (dn[0] > dnth) || (dn[1] > dnth) ||
                      (dn[2] > dnth) || (dn[3] > dnth);
    if (__any(need)) {
      const float* ajTb = ajT + (size_t)b * 128 * NN + t;
      for (int h = 0; h < NH; ++h) {
        float s[4] = {0.f, 0.f, 0.f, 0.f};
#pragma unroll
        for (int kc = 0; kc < 8; ++kc) {
          const float4 w2c = w2s4[h * 8 + kc];   // already -2*W2
          const int hk = h * NK + kc * 4;
          const float a0 = ajTb[(size_t)(hk + 0) * NN];
          const float a1 = ajTb[(size_t)(hk + 1) * NN];
          const float a2 = ajTb[(size_t)(hk + 2) * NN];
          const float a3 = ajTb[(size_t)(hk + 3) * NN];
#pragma unroll
          for (int r = 0; r < 4; ++r) {
            const float4 ac = ai2s4[r * 32 + h * 8 + kc];
            float z, rc, sr = s[r];
            z = ac.x + a0;
            rc = __builtin_amdgcn_rcpf(__builtin_amdgcn_exp2f(z) + 1.f);
            sr = fmaf(w2c.x, rc, sr);
            z = ac.y + a1;
            rc = __builtin_amdgcn_rcpf(__builtin_amdgcn_exp2f(z) + 1.f);
            sr = fmaf(w2c.y, rc, sr);
            z = ac.z + a2;
            rc = __builtin_amdgcn_rcpf(__builtin_amdgcn_exp2f(z) + 1.f);
            sr = fmaf(w2c.z, rc, sr);
            z = ac.w + a3;
            rc = __builtin_amdgcn_rcpf(__builtin_amdgcn_exp2f(z) + 1.f);
            sr = fmaf(w2c.w, rc, sr);
            s[r] = sr;
          }
        }
#pragma unroll
        for (int r = 0; r < 4; ++r) {
          const float si = s[r] + b2s[h];       // + (b2 + sum_k W2)
          const float e2 = __builtin_amdgcn_exp2f(si * L2E);
          const float lp = __builtin_amdgcn_logf(e2 + 1.f) * LN2V;
          const float sp = (si > 15.f) ? si : lp;   // softplus
          const float den = fmaf(2.f * sp, sp, EPSV);
          const float rr = __builtin_amdgcn_rcpf(den);
          adjv[r] += __builtin_amdgcn_exp2f(dn[r] * rr);
        }
      }
    }
  }
  {
    float4 v;
    v.x = adjv[0] * 0.25f; v.y = adjv[1] * 0.25f;
    v.z = adjv[2] * 0.25f; v.w = adjv[3] * 0.25f;
    adjs4[t] = v;
  }
  __syncthreads();

  // ---- Phase C: h_out = adj @ x (coalesced row reads) ----
  {
    const int dg = t & 31, jp = t >> 5;   // 16 j-groups of 32 j's
    float4 f0 = {0,0,0,0}, f1 = {0,0,0,0}, f2 = {0,0,0,0}, f3 = {0,0,0,0};
    const float* xb = x + (size_t)(b * NN) * ND;
    for (int u = 0; u < 32; ++u) {
      const int j = jp * 32 + u;
      const float4 a = adjs4[j];
      const float4 xv = ld4(xb + (size_t)j * ND + dg * 4);
      f0.x = fmaf(a.x, xv.x, f0.x); f0.y = fmaf(a.x, xv.y, f0.y);
      f0.z = fmaf(a.x, xv.z, f0.z); f0.w = fmaf(a.x, xv.w, f0.w);
      f1.x = fmaf(a.y, xv.x, f1.x); f1.y = fmaf(a.y, xv.y, f1.y);
      f1.z = fmaf(a.y, xv.z, f1.z); f1.w = fmaf(a.y, xv.w, f1.w);
      f2.x = fmaf(a.z, xv.x, f2.x); f2.y = fmaf(a.z, xv.y, f2.y);
      f2.z = fmaf(a.z, xv.z, f2.z); f2.w = fmaf(a.z, xv.w, f2.w);
      f3.x = fmaf(a.w, xv.x, f3.x); f3.y = fmaf(a.w, xv.y, f3.y);
      f3.z = fmaf(a.w, xv.z, f3.z); f3.w = fmaf(a.w, xv.w, f3.w);
    }
    float4* pc4 = reinterpret_cast<float4*>(pcbuf);
    pc4[jp * 128 + 0 * 32 + dg] = f0;
    pc4[jp * 128 + 1 * 32 + dg] = f1;
    pc4[jp * 128 + 2 * 32 + dg] = f2;
    pc4[jp * 128 + 3 * 32 + dg] = f3;
  }
  __syncthreads();
  {
    float v = 0.f;
#pragma unroll
    for (int jp = 0; jp < 16; ++jp) v += pcbuf[jp * 512 + t];
    hsT[t] = v;   // t = r*128 + e
  }
  __syncthreads();

  // ---- Phase D: out = h_out @ Wp + bp ----
  {
    const int d = t & 127, eh = t >> 7;
    float a0 = 0.f, a1 = 0.f, a2 = 0.f, a3 = 0.f;
    for (int ee = 0; ee < 32; ++ee) {
      const int e = eh * 32 + ee;
      const float w = Wp[(size_t)e * ND + d];
      a0 = fmaf(hsT[0 * 128 + e], w, a0);
      a1 = fmaf(hsT[1 * 128 + e], w, a1);
      a2 = fmaf(hsT[2 * 128 + e], w, a2);
      a3 = fmaf(hsT[3 * 128 + e], w, a3);
    }
    float* pd = pcbuf;
    pd[eh * 512 + 0 * 128 + d] = a0;
    pd[eh * 512 + 1 * 128 + d] = a1;
    pd[eh * 512 + 2 * 128 + d] = a2;
    pd[eh * 512 + 3 * 128 + d] = a3;
  }
  __syncthreads();
  {
    const int r = t >> 7, d = t & 127;
    const float v = pcbuf[0 * 512 + t] + pcbuf[1 * 512 + t] +
                    pcbuf[2 * 512 + t] + pcbuf[3 * 512 + t] + bp[d];
    out[(size_t)(b * NN + i0 + r) * ND + d] = v;
  }
}

// Fallback: fused kernel (R3-verified, row layouts), used if ws is too small.
__global__ __launch_bounds__(512, 4) void dgf_fused(
    const float* __restrict__ x, const float* __restrict__ W2,
    const float* __restrict__ b2, const float* __restrict__ Wp,
    const float* __restrict__ bp, const float* __restrict__ ai2,
    const float* __restrict__ aj2, const float* __restrict__ x2n,
    float* __restrict__ out) {
  __shared__ float4 xi4[4 * 32];
  __shared__ float4 ai2s4[4 * 32];
  __shared__ float4 w2s4[32];
  __shared__ float x2is[4];
  __shared__ float b2s[4];
  __shared__ float4 adjs4[512];
  __shared__ float pcbuf[16 * 512];
  __shared__ float hsT[4 * 128];
  const int t = threadIdx.x;
  const int blk = blockIdx.x;
  const int b = blk >> 7;
  const int i0 = (blk & 127) << 2;

  if (t < 128) {
    const int r = t >> 5;
    const int c = t & 31;
    xi4[t]   = ld4(x   + (size_t)(b * NN + i0 + r) * ND + c * 4);
    ai2s4[t] = ld4(ai2 + (size_t)(b * NN + i0 + r) * (NH * NK) + c * 4);
  } else if (t < 160) {
    const float4 w = ld4(W2 + (t - 128) * 4);
    float4 wn;
    wn.x = -2.f * w.x; wn.y = -2.f * w.y; wn.z = -2.f * w.z; wn.w = -2.f * w.w;
    w2s4[t - 128] = wn;
  } else if (t < 164) {
    x2is[t - 160] = x2n[b * NN + i0 + (t - 160)];
  } else if (t < 168) {
    const int h = t - 164;
    float sw = 0.f;
    for (int k = 0; k < NK; ++k) sw += W2[h * NK + k];
    b2s[h] = b2[h] + sw;
  }
  __syncthreads();

  float dn[4];
  {
    float g[4] = {0.f, 0.f, 0.f, 0.f};
    const float* xj = x + (size_t)(b * NN + t) * ND;
    for (int c = 0; c < 32; ++c) {
      const float4 a = ld4(xj + c * 4);
#pragma unroll
      for (int r = 0; r < 4; ++r) {
        const float4 xv = xi4[r * 32 + c];
        float u = g[r];
        u = fmaf(xv.x, a.x, u); u = fmaf(xv.y, a.y, u);
        u = fmaf(xv.z, a.z, u); u = fmaf(xv.w, a.w, u);
        g[r] = u;
      }
    }
    const float x2j = x2n[b * NN + t];
#pragma unroll
    for (int r = 0; r < 4; ++r)
      dn[r] = -L2E * fmaxf(x2is[r] + x2j - 2.f * g[r], 0.f);
  }

  float adjv[4] = {0.f, 0.f, 0.f, 0.f};
  {
    const float* ajp = aj2 + (size_t)(b * NN + t) * (NH * NK);
    for (int h = 0; h < NH; ++h) {
      float4 aj[8];
#pragma unroll
      for (int c = 0; c < 8; ++c) aj[c] = ld4(ajp + h * NK + c * 4);
      float s[4] = {0.f, 0.f, 0.f, 0.f};
#pragma unroll
      for (int kc = 0; kc < 8; ++kc) {
        const float4 w2c = w2s4[h * 8 + kc];
        const float4 ajc = aj[kc];
#pragma unroll
        for (int r = 0; r < 4; ++r) {
          const float4 ac = ai2s4[r * 32 + h * 8 + kc];
          float z, rc, sr = s[r];
          z = ac.x + ajc.x;
          rc = __builtin_amdgcn_rcpf(__builtin_amdgcn_exp2f(z) + 1.f);
          sr = fmaf(w2c.x, rc, sr);
          z = ac.y + ajc.y;
          rc = __builtin_amdgcn_rcpf(__builtin_amdgcn_exp2f(z) + 1.f);
          sr = fmaf(w2c.y, rc, sr);
          z = ac.z + ajc.z;
          rc = __builtin_amdgcn_rcpf(__builtin_amdgcn_exp2f(z) + 1.f);
          sr = fmaf(w2c.z, rc, sr);
          z = ac.w + ajc.w;
          rc = __builtin_amdgcn_rcpf(__builtin_amdgcn_exp2f(z) + 1.f);
          sr = fmaf(w2c.w, rc, sr);
          s[r] = sr;
        }
      }
#pragma unroll
      for (int r = 0; r < 4; ++r) {
        const float si = s[r] + b2s[h];
        const float e2 = __builtin_amdgcn_exp2f(si * L2E);
        const float lp = __builtin_amdgcn_logf(e2 + 1.f) * LN2V;
        const float sp = (si > 15.f) ? si : lp;
        const float den = fmaf(2.f * sp, sp, EPSV);
        const float rr = __builtin_amdgcn_rcpf(den);
        adjv[r] += __builtin_amdgcn_exp2f(dn[r] * rr);
      }
    }
  }
  {
    float4 v;
    v.x = adjv[0] * 0.25f; v.y = adjv[1] * 0.25f;
    v.z = adjv[2] * 0.25f; v.w = adjv[3] * 0.25f;
    adjs4[t] = v;
  }
  __syncthreads();

  {
    const int dg = t & 31, jp = t >> 5;
    float4 f0 = {0,0,0,0}, f1 = {0,0,0,0}, f2 = {0,0,0,0}, f3 = {0,0,0,0};
    const float* xb = x + (size_t)(b * NN) * ND;
    for (int u = 0; u < 32; ++u) {
      const int j = jp * 32 + u;
      const float4 a = adjs4[j];
      const float4 xv = ld4(xb + (size_t)j * ND + dg * 4);
      f0.x = fmaf(a.x, xv.x, f0.x); f0.y = fmaf(a.x, xv.y, f0.y);
      f0.z = fmaf(a.x, xv.z, f0.z); f0.w = fmaf(a.x, xv.w, f0.w);
      f1.x = fmaf(a.y, xv.x, f1.x); f1.y = fmaf(a.y, xv.y, f1.y);
      f1.z = fmaf(a.y, xv.z, f1.z); f1.w = fmaf(a.y, xv.w, f1.w);
      f2.x = fmaf(a.z, xv.x, f2.x); f2.y = fmaf(a.z, xv.y, f2.y);
      f2.z = fmaf(a.z, xv.z, f2.z); f2.w = fmaf(a.z, xv.w, f2.w);
      f3.x = fmaf(a.w, xv.x, f3.x); f3.y = fmaf(a.w, xv.y, f3.y);
      f3.z = fmaf(a.w, xv.z, f3.z); f3.w = fmaf(a.w, xv.w, f3.w);
    }
    float4* pc4 = reinterpret_cast<float4*>(pcbuf);
    pc4[jp * 128 + 0 * 32 + dg] = f0;
    pc4[jp * 128 + 1 * 32 + dg] = f1;
    pc4[jp * 128 + 2 * 32 + dg] = f2;
    pc4[jp * 128 + 3 * 32 + dg] = f3;
  }
  __syncthreads();
  {
    float v = 0.f;
#pragma unroll
    for (int jp = 0; jp < 16; ++jp) v += pcbuf[jp * 512 + t];
    hsT[t] = v;
  }
  __syncthreads();
  {
    const int d = t & 127, eh = t >> 7;
    float a0 = 0.f, a1 = 0.f, a2 = 0.f, a3 = 0.f;
    for (int ee = 0; ee < 32; ++ee) {
      const int e = eh * 32 + ee;
      const float w = Wp[(size_t)e * ND + d];
      a0 = fmaf(hsT[0 * 128 + e], w, a0);
      a1 = fmaf(hsT[1 * 128 + e], w, a1);
      a2 = fmaf(hsT[2 * 128 + e], w, a2);
      a3 = fmaf(hsT[3 * 128 + e], w, a3);
    }
    float* pd = pcbuf;
    pd[eh * 512 + 0 * 128 + d] = a0;
    pd[eh * 512 + 1 * 128 + d] = a1;
    pd[eh * 512 + 2 * 128 + d] = a2;
    pd[eh * 512 + 3 * 128 + d] = a3;
  }
  __syncthreads();
  {
    const int d = t & 127;
    const float v = pcbuf[0 * 512 + t] + pcbuf[1 * 512 + t] +
                    pcbuf[2 * 512 + t] + pcbuf[3 * 512 + t] + bp[d];
    const int r = t >> 7;
    out[(size_t)(b * NN + i0 + r) * ND + d] = v;
  }
}

extern "C" void kernel_launch(void* const* d_in, const int* in_sizes, int n_in,
                              void* d_out, int out_size, void* d_ws, size_t ws_size,
                              hipStream_t stream) {
  const float* x  = (const float*)d_in[0];
  const float* W1 = (const float*)d_in[1];
  const float* b1 = (const float*)d_in[2];
  const float* W2 = (const float*)d_in[3];
  const float* b2 = (const float*)d_in[4];
  const float* Wp = (const float*)d_in[5];
  const float* bp = (const float*)d_in[6];
  float* out = (float*)d_out;

  const size_t nProj = (size_t)NB * NN * NH * NK;   // 262144
  const size_t nX2   = (size_t)NB * NN;             // 2048
  const size_t nT    = (size_t)NB * ND * NN;        // 262144 (ajT and xT each)

  float* aj2 = (float*)d_ws;
  float* ai2 = aj2 + nProj;
  float* x2n = ai2 + nProj;
  float* dnt = x2n + nX2;           // 4 floats (1 used)
  float* ajT = dnt + 4;
  float* xT  = ajT + nT;

  const bool big = ws_size >= (2 * nProj + nX2 + 4 + 2 * nT) * sizeof(float);

  dgf_proj<<<NB * NN / 8, 256, 0, stream>>>(
      x, W1, b1, W2, b2, ai2, aj2, big ? ajT : nullptr, big ? xT : nullptr,
      x2n, dnt);

  if (big) {
    dgf_adj2<<<NB * (NN / 4), 512, 0, stream>>>(x, W2, b2, Wp, bp, ai2, ajT,
                                                xT, x2n, dnt, out);
  } else {
    dgf_fused<<<NB * (NN / 4), 512, 0, stream>>>(x, W2, b2, Wp, bp, ai2, aj2,
                                                 x2n, out);
  }
}